// Round 7
// baseline (536.785 us; speedup 1.0000x reference)
//
#include <hip/hip_runtime.h>

#define BB 4
#define CC 32
#define HH 128
#define WW 256
#define CR 85
#define EPSF 1e-5f

// Output offsets (elements): out0 @0, out1 @4194304, out2 @8388608, out3 @41943040
#define O1_OFF 4194304
#define O2_OFF 8388608
#define COST1 33554432   // elements per direction of cost / out2-3

typedef __attribute__((ext_vector_type(8))) short bf16x8;
typedef __attribute__((ext_vector_type(4))) float f32x4;
typedef __attribute__((ext_vector_type(4))) float f4v;

static __device__ __forceinline__ unsigned short f2bf(float f) {
    unsigned u = __float_as_uint(f);
    unsigned r = (u + 0x7FFFu + ((u >> 16) & 1u)) >> 16;   // RNE
    return (unsigned short)r;
}

// Sb swizzle: [32][128] f32, 16-B chunk XOR by (row&7). Writes 2-way (free),
// reads contiguous-permuted (conflict-free).
#define SBS(r, c) ((r) * 128 + (((((c) >> 2) ^ ((r) & 7)) << 2) | ((c) & 3)))

// ---------------- Fused half-row kernel ----------------
// block = (dir, bh, half): 2048 blocks, 4 tiles each. LDS exactly 40 KB ->
// 4 blocks/CU (16 waves), grid = 2 perfect rounds of 1024 resident blocks.
// Phase 1: BN-fold -> project K (full row, every thread: px t) and Q (this
// half's 128 px, split: thread t does 16 output channels of px ibase+(t&127)).
// Phase 2: per tile: MFMA from LDS Q/K -> Sb exchange (swizzled) -> band-add
// into prefetched cost -> nt store; next tile's cost prefetch interleaved.
__global__ __launch_bounds__(256, 4)
void pab_fused_half(const float* __restrict__ x_left, const float* __restrict__ x_right,
                    const float* __restrict__ cost,
                    const float* __restrict__ q_w, const float* __restrict__ q_b,
                    const float* __restrict__ q_gamma, const float* __restrict__ q_beta,
                    const float* __restrict__ q_mean, const float* __restrict__ q_var,
                    const float* __restrict__ k_w, const float* __restrict__ k_b,
                    const float* __restrict__ k_gamma, const float* __restrict__ k_beta,
                    const float* __restrict__ k_mean, const float* __restrict__ k_var,
                    float* __restrict__ out)
{
    __shared__ unsigned short Qs[128 * CC];  // 8 KB  [local px][ch]
    __shared__ unsigned short Ks[WW * CC];   // 16 KB [abs px][ch]
    __shared__ char smem[32 * 128 * 4];      // 16 KB: weights (ph1) / Sb (ph2)
    float* Sb = (float*)smem;
    float (*wqs)[CC] = (float(*)[CC])smem;            // [c][o], 4 KB
    float (*wks)[CC] = (float(*)[CC])(smem + 4096);   // 4 KB
    float* bqs = (float*)(smem + 8192);
    float* bks = (float*)(smem + 8320);
    float* sqs = (float*)(smem + 8448);
    float* sks = (float*)(smem + 8576);

    const int t    = threadIdx.x;
    const int bx   = blockIdx.x;
    const int dir  = bx >> 10;         // 0 = r2l, 1 = l2r
    const int bh   = (bx >> 1) & 511;
    const int half = bx & 1;
    const int b = bh >> 7, h = bh & 127;
    const int ibase = half * 128;      // first output row of this block

    const float* csrc = cost + (size_t)dir * COST1 + (size_t)bh * (WW * WW);
    float* odst = out + O2_OFF + (size_t)dir * COST1 + (size_t)bh * (WW * WW);
    const int rowlane = t >> 6;        // 0..3
    const int c4 = 4 * (t & 63);

    // ---- tile-0 cost prefetch: in flight across the whole projection phase ----
    f4v vbuf[8];
    #pragma unroll
    for (int p = 0; p < 8; ++p) {
        int rl = 4 * p + rowlane;
        vbuf[p] = __builtin_nontemporal_load((const f4v*)(csrc + (ibase + rl) * WW + c4));
    }

    // ---- phase 1a: BN fold ----
    if (t < CC) {
        float qs_ = q_gamma[t] * rsqrtf(q_var[t] + EPSF);
        float ks_ = k_gamma[t] * rsqrtf(k_var[t] + EPSF);
        sqs[t] = qs_; sks[t] = ks_;
        bqs[t] = q_b[t] * qs_ + q_beta[t] - q_mean[t] * qs_;
        bks[t] = k_b[t] * ks_ + k_beta[t] - k_mean[t] * ks_;
    }
    __syncthreads();
    for (int r = t; r < CC * CC; r += 256) {
        int o = r >> 5, c = r & 31;
        wqs[c][o] = q_w[r] * sqs[o];
        wks[c][o] = k_w[r] * sks[o];
    }
    __syncthreads();

    // dir0 (r2l): Q from left, K from right; dir1 (l2r): Q from right, K from left
    const float* xq = dir ? x_right : x_left;
    const float* xk = dir ? x_left  : x_right;
    float* outq = out + (dir ? O1_OFF : 0);

    // ---- phase 1b-K: every thread projects K for abs px t ----
    {
        float k[CC];
        #pragma unroll
        for (int o = 0; o < CC; ++o) k[o] = bks[o];
        const int xkbase = (b * CC * HH + h) * WW + t;
        #pragma unroll 4
        for (int c = 0; c < CC; ++c) {
            float xv = xk[xkbase + c * (HH * WW)];
            #pragma unroll
            for (int o = 0; o < CC; ++o) k[o] += xv * wks[c][o];
        }
        unsigned short* kdst = Ks + t * CC;
        #pragma unroll
        for (int g = 0; g < 4; ++g) {
            uint4 v;
            v.x = f2bf(k[8*g+0]) | ((unsigned)f2bf(k[8*g+1]) << 16);
            v.y = f2bf(k[8*g+2]) | ((unsigned)f2bf(k[8*g+3]) << 16);
            v.z = f2bf(k[8*g+4]) | ((unsigned)f2bf(k[8*g+5]) << 16);
            v.w = f2bf(k[8*g+6]) | ((unsigned)f2bf(k[8*g+7]) << 16);
            ((uint4*)kdst)[g] = v;
        }
    }

    // ---- phase 1b-Q: balanced split — thread t does output ch [oh*16, oh*16+16)
    // of local px (t&127); threads with t<128 also emit the 2*x output ----
    {
        const int lpx = t & 127;
        const int oh  = t >> 7;            // 0 or 1
        const int ob  = oh * 16;
        float q[16];
        #pragma unroll
        for (int o = 0; o < 16; ++o) q[o] = bqs[ob + o];
        const int xqbase = (b * CC * HH + h) * WW + ibase + lpx;
        #pragma unroll 4
        for (int c = 0; c < CC; ++c) {
            float xv = xq[xqbase + c * (HH * WW)];
            if (t < 128)
                __builtin_nontemporal_store(2.0f * xv, outq + xqbase + c * (HH * WW));
            #pragma unroll
            for (int o = 0; o < 16; ++o) q[o] += xv * wqs[c][ob + o];
        }
        unsigned short* qdst = Qs + lpx * CC + ob;
        #pragma unroll
        for (int g = 0; g < 2; ++g) {
            uint4 v;
            v.x = f2bf(q[8*g+0]) | ((unsigned)f2bf(q[8*g+1]) << 16);
            v.y = f2bf(q[8*g+2]) | ((unsigned)f2bf(q[8*g+3]) << 16);
            v.z = f2bf(q[8*g+4]) | ((unsigned)f2bf(q[8*g+5]) << 16);
            v.w = f2bf(q[8*g+6]) | ((unsigned)f2bf(q[8*g+7]) << 16);
            ((uint4*)qdst)[g] = v;
        }
    }
    __syncthreads();   // Qs/Ks ready; weights dead (Sb overwrites after next barrier)

    // ---- phase 2: 4 row-tiles ----
    const int w = t >> 6, lane = t & 63;
    const int quad = lane >> 4, l16 = lane & 15;
    const float inv32 = 1.0f / 32.0f;

    for (int tt = 0; tt < 4; ++tt) {
        const int i0 = ibase + tt * 32;             // absolute first row
        const int wbase = dir ? i0 : (i0 - 96);     // window cols [wbase, wbase+128)

        // fragments: Q local rows, K absolute cols (OOB -> zero frag)
        bf16x8 qf[2], kf[2];
        #pragma unroll
        for (int mt = 0; mt < 2; ++mt)
            qf[mt] = *(const bf16x8*)(Qs + (tt * 32 + 16 * mt + l16) * CC + quad * 8);
        #pragma unroll
        for (int nt = 0; nt < 2; ++nt) {
            int col = wbase + 32 * w + 16 * nt + l16;
            bf16x8 kv = {};
            if (col >= 0 && col < WW)
                kv = *(const bf16x8*)(Ks + col * CC + quad * 8);
            kf[nt] = kv;
        }

        f32x4 acc[2][2] = {};
        #pragma unroll
        for (int mt = 0; mt < 2; ++mt)
            #pragma unroll
            for (int nt = 0; nt < 2; ++nt)
                acc[mt][nt] = __builtin_amdgcn_mfma_f32_16x16x32_bf16(
                    qf[mt], kf[nt], acc[mt][nt], 0, 0, 0);

        __syncthreads();   // prev tile's Sb reads (or phase-1 weight reads) done

        // Sb exchange, swizzled
        #pragma unroll
        for (int mt = 0; mt < 2; ++mt)
            #pragma unroll
            for (int nt = 0; nt < 2; ++nt) {
                int cl = 32 * w + 16 * nt + l16;
                #pragma unroll
                for (int r = 0; r < 4; ++r) {
                    int row = 16 * mt + quad * 4 + r;
                    Sb[SBS(row, cl)] = acc[mt][nt][r];
                }
            }
        __syncthreads();

        // epilogue: band-add + nt store; interleave next tile's prefetch
        const int lc = c4 - wbase;
        const bool inwin = (lc >= 0 && lc < 128);
        #pragma unroll
        for (int p = 0; p < 8; ++p) {
            int rl = 4 * p + rowlane;
            int i = i0 + rl;
            f4v v = vbuf[p];
            if (inwin) {
                const f4v s = *(const f4v*)(Sb + rl * 128 + (((lc >> 2) ^ (rl & 7)) << 2));
                int d0 = dir ? (c4 + 0 - i) : (i - c4 - 0);
                int d1 = dir ? (c4 + 1 - i) : (i - c4 - 1);
                int d2 = dir ? (c4 + 2 - i) : (i - c4 - 2);
                int d3 = dir ? (c4 + 3 - i) : (i - c4 - 3);
                if (d0 >= 0 && d0 < CR) v[0] += s[0] * inv32;
                if (d1 >= 0 && d1 < CR) v[1] += s[1] * inv32;
                if (d2 >= 0 && d2 < CR) v[2] += s[2] * inv32;
                if (d3 >= 0 && d3 < CR) v[3] += s[3] * inv32;
            }
            __builtin_nontemporal_store(v, (f4v*)(odst + (size_t)i * WW + c4));
            if (tt < 3)
                vbuf[p] = __builtin_nontemporal_load(
                    (const f4v*)(csrc + (i0 + 32 + rl) * WW + c4));
        }
    }
}

extern "C" void kernel_launch(void* const* d_in, const int* in_sizes, int n_in,
                              void* d_out, int out_size, void* d_ws, size_t ws_size,
                              hipStream_t stream) {
    const float* x_left  = (const float*)d_in[0];
    const float* x_right = (const float*)d_in[1];
    const float* cost    = (const float*)d_in[2];
    const float* q_w     = (const float*)d_in[3];
    const float* q_b     = (const float*)d_in[4];
    const float* q_gamma = (const float*)d_in[5];
    const float* q_beta  = (const float*)d_in[6];
    const float* q_mean  = (const float*)d_in[7];
    const float* q_var   = (const float*)d_in[8];
    const float* k_w     = (const float*)d_in[9];
    const float* k_b     = (const float*)d_in[10];
    const float* k_gamma = (const float*)d_in[11];
    const float* k_beta  = (const float*)d_in[12];
    const float* k_mean  = (const float*)d_in[13];
    const float* k_var   = (const float*)d_in[14];
    float* out = (float*)d_out;

    pab_fused_half<<<dim3(2048), dim3(256), 0, stream>>>(
        x_left, x_right, cost,
        q_w, q_b, q_gamma, q_beta, q_mean, q_var,
        k_w, k_b, k_gamma, k_beta, k_mean, k_var,
        out);
}